// Round 14
// baseline (192.848 us; speedup 1.0000x reference)
//
#include <hip/hip_runtime.h>

#define N_NODES 100000
#define N_EDGES 1600000
#define D 64
#define NBUCKET 782              // ceil(N_NODES/128), bucket = 128 dst nodes
#define QCAP_B 2432              // per-bucket queue cap (mean ~2046, +8.5 sd)
#define EPB 2048                 // edges per sort block
#define SORT_BLOCKS 782          // ceil(N_EDGES/EPB) = 781.25 -> 782

typedef unsigned short u16;
typedef short bf16x8 __attribute__((ext_vector_type(8)));
typedef float f32x4  __attribute__((ext_vector_type(4)));

__device__ __forceinline__ u16 f2bf(float f) {
    unsigned u;
    __builtin_memcpy(&u, &f, 4);
    u = (u + 0x7FFFu + ((u >> 16) & 1u)) >> 16;
    return (u16)u;
}

// ---------------------------------------------------------------------------
// Block-level counting sort of 2048 edges into 782 bucket queues.
// v4 schedule: 782 blocks x 512 threads (vs 391x1024) — same total waves but
// block-tail imbalance drops from 2:1 to 4:3 across the 256 CUs, and barrier
// groups halve. Pair-per-thread wave-shfl scan over the 1024-padded counter
// table. Register-staged ei (4 edges/thread as two uint4). Fused x->bf16
// convert grid-strided across the kernel. The LAST block (512 edges only)
// additionally does the old misc work: dummy-row zero + weight frag pack.
// Entry packs (dst&127)<<17 | src.
// ---------------------------------------------------------------------------
__global__ __launch_bounds__(512) void sort_kernel(
    const int* __restrict__ ei, int* __restrict__ qtail,
    unsigned* __restrict__ queue, const float* __restrict__ x,
    u16* __restrict__ xb, const float* __restrict__ W1,
    const float* __restrict__ W2, u16* __restrict__ Wf,
    u16* __restrict__ hb)
{
    __shared__ int cnt[1024];
    __shared__ int base_s[1024];
    __shared__ int gbase[1024];
    __shared__ int run[1024];
    __shared__ unsigned staged[EPB];
    __shared__ int gposa[EPB];
    __shared__ int wpart[8];
    __shared__ int tot_s;

    int tid = threadIdx.x;
    int e0 = blockIdx.x * EPB;
    int lane = tid & 63, wv = tid >> 6;

    cnt[tid] = 0; cnt[tid + 512] = 0;
    run[tid] = 0; run[tid + 512] = 0;

    // ---- misc fold (last block only: 512 edges, least loaded): dummy rows
    //      + W1/W2 -> bf16 MFMA B-fragment pack ----
    if (blockIdx.x == SORT_BLOCKS - 1) {
        if (tid < 32) {
            ((unsigned*)(xb + (size_t)N_NODES * D))[tid] = 0;
            ((unsigned*)(hb + (size_t)N_NODES * D))[tid] = 0;
        }
        for (int t = tid; t < 16 * 64; t += 512) {
            int f = t >> 6, ln = t & 63;
            int layer = f >> 3, ct = (f >> 1) & 3, kf = f & 1;
            const float* W = layer ? W2 : W1;
            int col = ct * 16 + (ln & 15);
            int krow = kf * 32 + (ln >> 4) * 8;
            u16* o = Wf + f * 512 + ln * 8;
#pragma unroll
            for (int j = 0; j < 8; ++j)
                o[j] = f2bf(W[(krow + j) * D + col]);
        }
    }

    // ---- fused convert slice: x (f32) -> xb (bf16), ~4 float4/thread ----
    for (int i = blockIdx.x * 512 + tid; i < N_NODES * D / 4;
         i += SORT_BLOCKS * 512) {
        float4 v = ((const float4*)x)[i];
        ushort4 o;
        o.x = f2bf(v.x); o.y = f2bf(v.y); o.z = f2bf(v.z); o.w = f2bf(v.w);
        ((ushort4*)xb)[i] = o;
    }

    // ---- register-stage this thread's 4 edges + hist ----
    int limit = min(EPB, N_EDGES - e0);   // 2048, or 512 for the last block
    int g0 = 4 * tid;
    bool have = g0 < limit;
    uint4 src4, dst4;
    __syncthreads();   // cnt/run zero visible
    if (have) {
        src4 = *(const uint4*)(ei + e0 + g0);
        dst4 = *(const uint4*)(ei + N_EDGES + e0 + g0);
        atomicAdd(&cnt[((int)dst4.x) >> 7], 1);
        atomicAdd(&cnt[((int)dst4.y) >> 7], 1);
        atomicAdd(&cnt[((int)dst4.z) >> 7], 1);
        atomicAdd(&cnt[((int)dst4.w) >> 7], 1);
    }
    __syncthreads();

    // ---- 1024-wide exclusive scan, pair per thread (2t, 2t+1) ----
    int c0 = cnt[2 * tid], c1 = cnt[2 * tid + 1];
    int sum = c0 + c1;
    int inc = sum;
    for (int off = 1; off < 64; off <<= 1) {
        int t = __shfl_up(inc, off);
        if (lane >= off) inc += t;
    }
    if (lane == 63) wpart[wv] = inc;
    __syncthreads();
    if (tid < 64) {
        int p = (lane < 8) ? wpart[lane] : 0;
        int ps = p;
        for (int off = 1; off < 8; off <<= 1) {
            int t = __shfl_up(ps, off);
            if (lane >= off) ps += t;
        }
        if (lane < 8) wpart[lane] = ps - p;   // exclusive wave base
    }
    __syncthreads();
    int pb = wpart[wv] + inc - sum;           // exclusive prefix of the pair
    base_s[2 * tid]     = pb;
    base_s[2 * tid + 1] = pb + c0;
    if (tid == 511) tot_s = wpart[7] + inc;
    // ---- reserve global queue space (one atomic per nonempty bucket) ----
    for (int b = tid; b < NBUCKET; b += 512)
        if (cnt[b] > 0) gbase[b] = atomicAdd(&qtail[b], cnt[b]);
    __syncthreads();

    // ---- scatter into bucket-sorted LDS staging (from registers) ----
    if (have) {
        int ss[4] = {(int)src4.x, (int)src4.y, (int)src4.z, (int)src4.w};
        int dd[4] = {(int)dst4.x, (int)dst4.y, (int)dst4.z, (int)dst4.w};
#pragma unroll
        for (int q = 0; q < 4; ++q) {
            int b = dd[q] >> 7;
            int r = atomicAdd(&run[b], 1);
            int slot = base_s[b] + r;
            staged[slot] = ((unsigned)(dd[q] & 127) << 17) | (unsigned)ss[q];
            int gp = gbase[b] + r;
            gposa[slot] = (gp < QCAP_B) ? b * QCAP_B + gp : -1;
        }
    }
    __syncthreads();

    // ---- copy out (bucket-contiguous runs): 4 iters ----
    int total = tot_s;
    for (int i = tid; i < total; i += 512) {
        int gp = gposa[i];
        if (gp >= 0) queue[gp] = staged[i];
    }
}

// ---------------------------------------------------------------------------
// Per-bucket LDS counting sort -> exact CSR (r11, verbatim). 128-node
// buckets, 782 blocks x 512 threads. Zero global atomics.
// ---------------------------------------------------------------------------
__global__ __launch_bounds__(512) void bin3_kernel(
    const unsigned* __restrict__ queue, const int* __restrict__ qtail,
    int* __restrict__ cnt_out, int* __restrict__ row_start,
    int* __restrict__ sorted_src)
{
    __shared__ int cnt[128];
    __shared__ int ebase[128];
    __shared__ int run[128];
    __shared__ unsigned staged[QCAP_B];
    __shared__ int wpart[2];

    int tid = threadIdx.x;
    int b = blockIdx.x;
    int lane = tid & 63, wv = tid >> 6;

    if (tid < 128) { cnt[tid] = 0; run[tid] = 0; }
    __syncthreads();

    int n = min(qtail[b], QCAP_B);
    const unsigned* q = queue + (size_t)b * QCAP_B;

    for (int i = tid; i < n; i += 512) {
        unsigned e = q[i];
        staged[i] = e;
        atomicAdd(&cnt[e >> 17], 1);
    }
    __syncthreads();

    int inc = 0, v = 0;
    if (tid < 128) {
        v = cnt[tid];
        inc = v;
        for (int off = 1; off < 64; off <<= 1) {
            int t = __shfl_up(inc, off);
            if (lane >= off) inc += t;
        }
        if (lane == 63) wpart[wv] = inc;
    }
    __syncthreads();
    if (tid == 0) { int a = wpart[0]; wpart[0] = 0; wpart[1] = a; }
    __syncthreads();

    int gb = b * QCAP_B;
    if (tid < 128) {
        int eb = wpart[wv] + inc - v;
        ebase[tid] = eb;
        int node = b * 128 + tid;
        if (node < N_NODES) {
            cnt_out[node] = v;
            row_start[node] = gb + eb;
        }
    }
    __syncthreads();

    for (int i = tid; i < n; i += 512) {
        unsigned e = staged[i];
        int r = (int)(e >> 17);
        int k = atomicAdd(&run[r], 1);
        sorted_src[gb + ebase[r] + k] = (int)(e & 0x1FFFFu);
    }
}

// ---------------------------------------------------------------------------
// FUSED gather + 2-layer MFMA MLP (r13, verbatim): r1 gather geometry +
// within-block degree-balanced wave assignment + LDS-resident MLP.
// ---------------------------------------------------------------------------
#define XS 72   // u16 stride for LDS feature rows (144 B)

template <int WRITE_BF16>
__global__ __launch_bounds__(256) void gin_fused_kernel(
    const u16* __restrict__ xin, const int* __restrict__ cnt_arr,
    const int* __restrict__ row_start, const int* __restrict__ sorted_src,
    const u16* __restrict__ Wf, const float* __restrict__ b1,
    const float* __restrict__ b2, float* __restrict__ outf,
    u16* __restrict__ outb)
{
    __shared__ u16 xrow[32 * XS];   // 4608 B: gathered rows (bf16), by node off
    __shared__ u16 hrow[32 * XS];   // 4608 B: hidden rows (bf16), by node off
    __shared__ int sdeg[32];
    __shared__ unsigned char sperm[32];   // slot -> node offset, deg-ranked

    int tid  = threadIdx.x;
    int lane = tid & 63;
    int w    = tid >> 6;
    int g    = lane >> 3;        // group slot within wave
    int k    = lane & 7;         // 16B chunk within row / edge slot in batch
    int nbase = blockIdx.x * 32; // 3125 blocks * 32 = 100000 exact

    // ---- phase 0: degree-rank the block's 32 nodes ----
    if (tid < 32) sdeg[tid] = cnt_arr[nbase + tid];
    __syncthreads();
    if (tid < 32) {
        int myd = sdeg[tid];
        int rank = 0;
#pragma unroll
        for (int j = 0; j < 32; ++j) {
            int dj = sdeg[j];
            rank += (dj > myd) || (dj == myd && j < tid);
        }
        sperm[rank] = (unsigned char)tid;   // rank 0 = highest degree
    }
    __syncthreads();

    int noff = sperm[w * 8 + g];            // this slot's node offset
    int node = nbase + noff;

    // ================= phase 1: gather (r1 mechanics) =====================
    int cnt  = cnt_arr[node];
    int base = row_start[node];

    const uint4 sv = *(const uint4*)(xin + ((size_t)node * D + k * 8));
    float accl[4], acch[4];
#pragma unroll
    for (int i = 0; i < 4; ++i) {
        unsigned d = ((const unsigned*)&sv)[i];
        unsigned lo = d << 16, hi = d & 0xFFFF0000u;
        __builtin_memcpy(&accl[i], &lo, 4);
        __builtin_memcpy(&acch[i], &hi, 4);
    }

    // wave max degree across the 8 slots (similar degrees -> tight bound)
    int mc = cnt;
    mc = max(mc, __shfl_xor(mc, 8));
    mc = max(mc, __shfl_xor(mc, 16));
    mc = max(mc, __shfl_xor(mc, 32));

    int lb4 = (lane & 56) << 2;  // byte addr of group's lane 0 for bpermute

    for (int c = 0; c < mc; c += 8) {
        int s = (c + k < cnt) ? sorted_src[base + c + k] : N_NODES;

        uint4 v[8];
#pragma unroll
        for (int j = 0; j < 8; ++j) {
            int idx = __builtin_amdgcn_ds_bpermute(lb4 + 4 * j, s);
            v[j] = *(const uint4*)(xin + (((size_t)(unsigned)idx) * D + (k << 3)));
        }
#pragma unroll
        for (int j = 0; j < 8; ++j) {
#pragma unroll
            for (int i = 0; i < 4; ++i) {
                unsigned d = ((const unsigned*)&v[j])[i];
                unsigned lo = d << 16, hi = d & 0xFFFF0000u;
                float fl, fh;
                __builtin_memcpy(&fl, &lo, 4);
                __builtin_memcpy(&fh, &hi, 4);
                accl[i] += fl;
                acch[i] += fh;
            }
        }
    }

    // pack to bf16, store at the node's own LDS row (permutation-agnostic)
    {
        unsigned outp[4];
#pragma unroll
        for (int i = 0; i < 4; ++i)
            outp[i] = (unsigned)f2bf(accl[i]) | ((unsigned)f2bf(acch[i]) << 16);
        *(uint4*)&xrow[noff * XS + k * 8] = *(const uint4*)outp;
    }
    __syncthreads();

    // ================= phase 2: MLP (wave w -> group gr, ct pair) ==========
    int quad = lane >> 4;
    int l16  = lane & 15;
    int gr   = w & 1;            // node group: rows gr*16 .. gr*16+15
    int ct0  = (w >> 1) * 2;     // this wave's two output-column tiles

    // ---- layer 1: u = relu(xrow @ W1 + b1) ----
    const u16* xp = &xrow[(gr * 16 + l16) * XS + quad * 8];
    bf16x8 a0 = *(const bf16x8*)xp;          // k = quad*8+j
    bf16x8 a1 = *(const bf16x8*)(xp + 32);   // k = 32+quad*8+j

    f32x4 acc[2];
#pragma unroll
    for (int cc = 0; cc < 2; ++cc) {
        int ct = ct0 + cc;
        float bv = b1[ct * 16 + l16];
        acc[cc] = (f32x4){bv, bv, bv, bv};
        bf16x8 bf0 = *(const bf16x8*)(Wf + (size_t)((0 * 4 + ct) * 2 + 0) * 512 + lane * 8);
        bf16x8 bf1 = *(const bf16x8*)(Wf + (size_t)((0 * 4 + ct) * 2 + 1) * 512 + lane * 8);
        acc[cc] = __builtin_amdgcn_mfma_f32_16x16x32_bf16(a0, bf0, acc[cc], 0, 0, 0);
        acc[cc] = __builtin_amdgcn_mfma_f32_16x16x32_bf16(a1, bf1, acc[cc], 0, 0, 0);
    }

    // relu -> bf16 -> LDS hidden rows (C-layout: row=quad*4+r, col=ct*16+l16)
#pragma unroll
    for (int cc = 0; cc < 2; ++cc)
#pragma unroll
        for (int r = 0; r < 4; ++r)
            hrow[(gr * 16 + quad * 4 + r) * XS + (ct0 + cc) * 16 + l16] =
                f2bf(fmaxf(acc[cc][r], 0.f));
    __syncthreads();

    // ---- layer 2: v = u @ W2 + b2 ----
    const u16* up = &hrow[(gr * 16 + l16) * XS + quad * 8];
    bf16x8 u0 = *(const bf16x8*)up;
    bf16x8 u1 = *(const bf16x8*)(up + 32);

#pragma unroll
    for (int cc = 0; cc < 2; ++cc) {
        int ct = ct0 + cc;
        float bv = b2[ct * 16 + l16];
        acc[cc] = (f32x4){bv, bv, bv, bv};
        bf16x8 bf0 = *(const bf16x8*)(Wf + (size_t)((1 * 4 + ct) * 2 + 0) * 512 + lane * 8);
        bf16x8 bf1 = *(const bf16x8*)(Wf + (size_t)((1 * 4 + ct) * 2 + 1) * 512 + lane * 8);
        acc[cc] = __builtin_amdgcn_mfma_f32_16x16x32_bf16(u0, bf0, acc[cc], 0, 0, 0);
        acc[cc] = __builtin_amdgcn_mfma_f32_16x16x32_bf16(u1, bf1, acc[cc], 0, 0, 0);
    }

    // epilogue (C-layout scatter; 16-lane groups write contiguous runs)
#pragma unroll
    for (int r = 0; r < 4; ++r) {
        int nd = nbase + gr * 16 + quad * 4 + r;
#pragma unroll
        for (int cc = 0; cc < 2; ++cc) {
            int ct = ct0 + cc;
            if (WRITE_BF16)
                outb[(size_t)nd * D + ct * 16 + l16] = f2bf(fmaxf(acc[cc][r], 0.f));
            else
                outf[(size_t)nd * D + ct * 16 + l16] = acc[cc][r];
        }
    }
}

extern "C" void kernel_launch(void* const* d_in, const int* in_sizes, int n_in,
                              void* d_out, int out_size, void* d_ws, size_t ws_size,
                              hipStream_t stream)
{
    const float* x  = (const float*)d_in[0];
    const int*   ei = (const int*)d_in[1];
    const float* W1 = (const float*)d_in[2];
    const float* b1 = (const float*)d_in[3];
    const float* W2 = (const float*)d_in[4];
    const float* b2 = (const float*)d_in[5];
    float* out = (float*)d_out;

    // workspace (~41.6 MB):
    //   qtail(1024) | cnt(100096) | row_start(100096)
    //   queue (782*2432 u32) | sorted_src (782*2432 int)
    //   Wf (8192 u16) | hb ((N+1) rows bf16) | xb ((N+1) rows bf16)
    int* qtail      = (int*)d_ws;
    int* cnt_arr    = qtail + 1024;
    int* row_start  = cnt_arr + 100096;
    unsigned* queue = (unsigned*)(row_start + 100096);
    int* sorted_src = (int*)(queue + (size_t)NBUCKET * QCAP_B);
    u16* Wf         = (u16*)(sorted_src + (size_t)NBUCKET * QCAP_B);
    u16* hb_b       = Wf + 8192;
    u16* xb_b       = hb_b + (size_t)(N_NODES + 1) * D;

    const int fused_blocks = (N_NODES + 31) / 32;   // 3125 (32 nodes/block)

    // ---- prep: qtail zero (4KB memset), then sort(+convert+misc fold) ----
    hipMemsetAsync(qtail, 0, 1024 * sizeof(int), stream);
    sort_kernel<<<SORT_BLOCKS, 512, 0, stream>>>(
        ei, qtail, queue, x, xb_b, W1, W2, Wf, hb_b);
    bin3_kernel<<<NBUCKET, 512, 0, stream>>>(queue, qtail, cnt_arr, row_start, sorted_src);

    // ---- layer 1: hb = relu(MLP(xb + gather(xb))) ----
    gin_fused_kernel<1><<<fused_blocks, 256, 0, stream>>>(
        xb_b, cnt_arr, row_start, sorted_src, Wf, b1, b2, nullptr, hb_b);

    // ---- layer 2: out = MLP(hb + gather(hb)) ----
    gin_fused_kernel<0><<<fused_blocks, 256, 0, stream>>>(
        hb_b, cnt_arr, row_start, sorted_src, Wf, b1, b2, out, nullptr);
}

// Round 15
// 182.017 us; speedup vs baseline: 1.0595x; 1.0595x over previous
//
#include <hip/hip_runtime.h>

#define N_NODES 100000
#define N_EDGES 1600000
#define D 64
#define NBUCKET 782              // ceil(N_NODES/128), bucket = 128 dst nodes
#define QCAP_B 2432              // per-bucket queue cap (mean ~2046, +8.5 sd)
#define EPB 4096                 // edges per sort block
#define SORT_BLOCKS 391          // ceil(N_EDGES/EPB)

typedef unsigned short u16;
typedef short bf16x8 __attribute__((ext_vector_type(8)));
typedef float f32x4  __attribute__((ext_vector_type(4)));

__device__ __forceinline__ u16 f2bf(float f) {
    unsigned u;
    __builtin_memcpy(&u, &f, 4);
    u = (u + 0x7FFFu + ((u >> 16) & 1u)) >> 16;
    return (u16)u;
}

// ---------------------------------------------------------------------------
// Tiny prep (1 block): qtail zero (must precede sort's atomics), dummy-row
// zero in BOTH feature buffers, W1/W2 -> bf16 MFMA B-fragment pack.
// frag f = (layer*4 + ct)*2 + kf holds B[k=kf*32+quad*8+j][n=ct*16+(lane&15)]
// at u16 offset f*512 + lane*8 + j.
// (r14 showed folding this into sort is not a win — keep as its own kernel.)
// ---------------------------------------------------------------------------
__global__ __launch_bounds__(256) void misc_kernel(
    const float* __restrict__ W1, const float* __restrict__ W2,
    u16* __restrict__ Wf, int* __restrict__ qtail,
    u16* __restrict__ xb, u16* __restrict__ hb)
{
    int tid = threadIdx.x;
#pragma unroll
    for (int q = 0; q < 4; ++q)
        qtail[tid + q * 256] = 0;
    if (tid < 32) {
        ((unsigned*)(xb + (size_t)N_NODES * D))[tid] = 0;
        ((unsigned*)(hb + (size_t)N_NODES * D))[tid] = 0;
    }
#pragma unroll
    for (int t = tid; t < 16 * 64; t += 256) {
        int f = t >> 6, lane = t & 63;
        int layer = f >> 3, ct = (f >> 1) & 3, kf = f & 1;
        const float* W = layer ? W2 : W1;
        int col = ct * 16 + (lane & 15);
        int krow = kf * 32 + (lane >> 4) * 8;
        u16* o = Wf + f * 512 + lane * 8;
#pragma unroll
        for (int j = 0; j < 8; ++j)
            o[j] = f2bf(W[(krow + j) * D + col]);
    }
}

// ---------------------------------------------------------------------------
// Block-level counting sort of 4096 edges into 782 bucket queues (r11/r13,
// verbatim — r14's 782x512 split regressed: 2x barriers + 2x qtail atomics).
// 1024 threads, 16-wave shfl scan, register-staged ei, fused x->bf16
// convert. Entry packs (dst&127)<<17 | src.
// ---------------------------------------------------------------------------
__global__ __launch_bounds__(1024) void sort_kernel(
    const int* __restrict__ ei, int* __restrict__ qtail,
    unsigned* __restrict__ queue, const float* __restrict__ x,
    u16* __restrict__ xb)
{
    __shared__ int cnt[1024];
    __shared__ int base_s[1024];
    __shared__ int gbase[1024];
    __shared__ int run[1024];
    __shared__ unsigned staged[EPB];
    __shared__ int gposa[EPB];
    __shared__ int wpart[16];
    __shared__ int tot_s;

    int tid = threadIdx.x;
    int e0 = blockIdx.x * EPB;
    int lane = tid & 63, wv = tid >> 6;

    cnt[tid] = 0; run[tid] = 0;

    // ---- fused convert slice: x (f32) -> xb (bf16), ~4 float4/thread ----
    for (int i = blockIdx.x * 1024 + tid; i < N_NODES * D / 4;
         i += SORT_BLOCKS * 1024) {
        float4 v = ((const float4*)x)[i];
        ushort4 o;
        o.x = f2bf(v.x); o.y = f2bf(v.y); o.z = f2bf(v.z); o.w = f2bf(v.w);
        ((ushort4*)xb)[i] = o;
    }

    // ---- register-stage this thread's 4 edges + hist ----
    int limit = min(EPB, N_EDGES - e0);   // 4096 or 2560 (both %4 == 0)
    int g0 = 4 * tid;
    bool have = g0 < limit;
    uint4 src4, dst4;
    __syncthreads();   // cnt/run zero visible
    if (have) {
        src4 = *(const uint4*)(ei + e0 + g0);
        dst4 = *(const uint4*)(ei + N_EDGES + e0 + g0);
        atomicAdd(&cnt[((int)dst4.x) >> 7], 1);
        atomicAdd(&cnt[((int)dst4.y) >> 7], 1);
        atomicAdd(&cnt[((int)dst4.z) >> 7], 1);
        atomicAdd(&cnt[((int)dst4.w) >> 7], 1);
    }
    __syncthreads();

    // ---- 1024-wide exclusive scan: 16 waves shfl-scan 64 each + combine ----
    int v = cnt[tid];
    int inc = v;
    for (int off = 1; off < 64; off <<= 1) {
        int t = __shfl_up(inc, off);
        if (lane >= off) inc += t;
    }
    if (lane == 63) wpart[wv] = inc;
    __syncthreads();
    if (tid < 64) {
        int p = (lane < 16) ? wpart[lane] : 0;
        int ps = p;
        for (int off = 1; off < 16; off <<= 1) {
            int t = __shfl_up(ps, off);
            if (lane >= off) ps += t;
        }
        if (lane < 16) wpart[lane] = ps - p;   // exclusive wave base
    }
    __syncthreads();
    base_s[tid] = wpart[wv] + inc - v;         // exclusive prefix
    if (tid == 1023) tot_s = wpart[15] + inc;
    // ---- reserve global queue space (one atomic per nonempty bucket) ----
    if (tid < NBUCKET && cnt[tid] > 0)
        gbase[tid] = atomicAdd(&qtail[tid], cnt[tid]);
    __syncthreads();

    // ---- scatter into bucket-sorted LDS staging (from registers) ----
    if (have) {
        int ss[4] = {(int)src4.x, (int)src4.y, (int)src4.z, (int)src4.w};
        int dd[4] = {(int)dst4.x, (int)dst4.y, (int)dst4.z, (int)dst4.w};
#pragma unroll
        for (int q = 0; q < 4; ++q) {
            int b = dd[q] >> 7;
            int r = atomicAdd(&run[b], 1);
            int slot = base_s[b] + r;
            staged[slot] = ((unsigned)(dd[q] & 127) << 17) | (unsigned)ss[q];
            int gp = gbase[b] + r;
            gposa[slot] = (gp < QCAP_B) ? b * QCAP_B + gp : -1;
        }
    }
    __syncthreads();

    // ---- copy out (bucket-contiguous runs): 4 iters ----
    int total = tot_s;
    for (int i = tid; i < total; i += 1024) {
        int gp = gposa[i];
        if (gp >= 0) queue[gp] = staged[i];
    }
}

// ---------------------------------------------------------------------------
// Per-bucket LDS counting sort -> exact CSR (r11, verbatim). 128-node
// buckets, 782 blocks x 512 threads. Zero global atomics.
// ---------------------------------------------------------------------------
__global__ __launch_bounds__(512) void bin3_kernel(
    const unsigned* __restrict__ queue, const int* __restrict__ qtail,
    int* __restrict__ cnt_out, int* __restrict__ row_start,
    int* __restrict__ sorted_src)
{
    __shared__ int cnt[128];
    __shared__ int ebase[128];
    __shared__ int run[128];
    __shared__ unsigned staged[QCAP_B];
    __shared__ int wpart[2];

    int tid = threadIdx.x;
    int b = blockIdx.x;
    int lane = tid & 63, wv = tid >> 6;

    if (tid < 128) { cnt[tid] = 0; run[tid] = 0; }
    __syncthreads();

    int n = min(qtail[b], QCAP_B);
    const unsigned* q = queue + (size_t)b * QCAP_B;

    for (int i = tid; i < n; i += 512) {
        unsigned e = q[i];
        staged[i] = e;
        atomicAdd(&cnt[e >> 17], 1);
    }
    __syncthreads();

    int inc = 0, v = 0;
    if (tid < 128) {
        v = cnt[tid];
        inc = v;
        for (int off = 1; off < 64; off <<= 1) {
            int t = __shfl_up(inc, off);
            if (lane >= off) inc += t;
        }
        if (lane == 63) wpart[wv] = inc;
    }
    __syncthreads();
    if (tid == 0) { int a = wpart[0]; wpart[0] = 0; wpart[1] = a; }
    __syncthreads();

    int gb = b * QCAP_B;
    if (tid < 128) {
        int eb = wpart[wv] + inc - v;
        ebase[tid] = eb;
        int node = b * 128 + tid;
        if (node < N_NODES) {
            cnt_out[node] = v;
            row_start[node] = gb + eb;
        }
    }
    __syncthreads();

    for (int i = tid; i < n; i += 512) {
        unsigned e = staged[i];
        int r = (int)(e >> 17);
        int k = atomicAdd(&run[r], 1);
        sorted_src[gb + ebase[r] + k] = (int)(e & 0x1FFFFu);
    }
}

// ---------------------------------------------------------------------------
// FUSED gather + 2-layer MFMA MLP (r13, verbatim): r1 gather geometry +
// within-block degree-balanced wave assignment + LDS-resident MLP.
// ---------------------------------------------------------------------------
#define XS 72   // u16 stride for LDS feature rows (144 B)

template <int WRITE_BF16>
__global__ __launch_bounds__(256) void gin_fused_kernel(
    const u16* __restrict__ xin, const int* __restrict__ cnt_arr,
    const int* __restrict__ row_start, const int* __restrict__ sorted_src,
    const u16* __restrict__ Wf, const float* __restrict__ b1,
    const float* __restrict__ b2, float* __restrict__ outf,
    u16* __restrict__ outb)
{
    __shared__ u16 xrow[32 * XS];   // 4608 B: gathered rows (bf16), by node off
    __shared__ u16 hrow[32 * XS];   // 4608 B: hidden rows (bf16), by node off
    __shared__ int sdeg[32];
    __shared__ unsigned char sperm[32];   // slot -> node offset, deg-ranked

    int tid  = threadIdx.x;
    int lane = tid & 63;
    int w    = tid >> 6;
    int g    = lane >> 3;        // group slot within wave
    int k    = lane & 7;         // 16B chunk within row / edge slot in batch
    int nbase = blockIdx.x * 32; // 3125 blocks * 32 = 100000 exact

    // ---- phase 0: degree-rank the block's 32 nodes ----
    if (tid < 32) sdeg[tid] = cnt_arr[nbase + tid];
    __syncthreads();
    if (tid < 32) {
        int myd = sdeg[tid];
        int rank = 0;
#pragma unroll
        for (int j = 0; j < 32; ++j) {
            int dj = sdeg[j];
            rank += (dj > myd) || (dj == myd && j < tid);
        }
        sperm[rank] = (unsigned char)tid;   // rank 0 = highest degree
    }
    __syncthreads();

    int noff = sperm[w * 8 + g];            // this slot's node offset
    int node = nbase + noff;

    // ================= phase 1: gather (r1 mechanics) =====================
    int cnt  = cnt_arr[node];
    int base = row_start[node];

    const uint4 sv = *(const uint4*)(xin + ((size_t)node * D + k * 8));
    float accl[4], acch[4];
#pragma unroll
    for (int i = 0; i < 4; ++i) {
        unsigned d = ((const unsigned*)&sv)[i];
        unsigned lo = d << 16, hi = d & 0xFFFF0000u;
        __builtin_memcpy(&accl[i], &lo, 4);
        __builtin_memcpy(&acch[i], &hi, 4);
    }

    // wave max degree across the 8 slots (similar degrees -> tight bound)
    int mc = cnt;
    mc = max(mc, __shfl_xor(mc, 8));
    mc = max(mc, __shfl_xor(mc, 16));
    mc = max(mc, __shfl_xor(mc, 32));

    int lb4 = (lane & 56) << 2;  // byte addr of group's lane 0 for bpermute

    for (int c = 0; c < mc; c += 8) {
        int s = (c + k < cnt) ? sorted_src[base + c + k] : N_NODES;

        uint4 v[8];
#pragma unroll
        for (int j = 0; j < 8; ++j) {
            int idx = __builtin_amdgcn_ds_bpermute(lb4 + 4 * j, s);
            v[j] = *(const uint4*)(xin + (((size_t)(unsigned)idx) * D + (k << 3)));
        }
#pragma unroll
        for (int j = 0; j < 8; ++j) {
#pragma unroll
            for (int i = 0; i < 4; ++i) {
                unsigned d = ((const unsigned*)&v[j])[i];
                unsigned lo = d << 16, hi = d & 0xFFFF0000u;
                float fl, fh;
                __builtin_memcpy(&fl, &lo, 4);
                __builtin_memcpy(&fh, &hi, 4);
                accl[i] += fl;
                acch[i] += fh;
            }
        }
    }

    // pack to bf16, store at the node's own LDS row (permutation-agnostic)
    {
        unsigned outp[4];
#pragma unroll
        for (int i = 0; i < 4; ++i)
            outp[i] = (unsigned)f2bf(accl[i]) | ((unsigned)f2bf(acch[i]) << 16);
        *(uint4*)&xrow[noff * XS + k * 8] = *(const uint4*)outp;
    }
    __syncthreads();

    // ================= phase 2: MLP (wave w -> group gr, ct pair) ==========
    int quad = lane >> 4;
    int l16  = lane & 15;
    int gr   = w & 1;            // node group: rows gr*16 .. gr*16+15
    int ct0  = (w >> 1) * 2;     // this wave's two output-column tiles

    // ---- layer 1: u = relu(xrow @ W1 + b1) ----
    const u16* xp = &xrow[(gr * 16 + l16) * XS + quad * 8];
    bf16x8 a0 = *(const bf16x8*)xp;          // k = quad*8+j
    bf16x8 a1 = *(const bf16x8*)(xp + 32);   // k = 32+quad*8+j

    f32x4 acc[2];
#pragma unroll
    for (int cc = 0; cc < 2; ++cc) {
        int ct = ct0 + cc;
        float bv = b1[ct * 16 + l16];
        acc[cc] = (f32x4){bv, bv, bv, bv};
        bf16x8 bf0 = *(const bf16x8*)(Wf + (size_t)((0 * 4 + ct) * 2 + 0) * 512 + lane * 8);
        bf16x8 bf1 = *(const bf16x8*)(Wf + (size_t)((0 * 4 + ct) * 2 + 1) * 512 + lane * 8);
        acc[cc] = __builtin_amdgcn_mfma_f32_16x16x32_bf16(a0, bf0, acc[cc], 0, 0, 0);
        acc[cc] = __builtin_amdgcn_mfma_f32_16x16x32_bf16(a1, bf1, acc[cc], 0, 0, 0);
    }

    // relu -> bf16 -> LDS hidden rows (C-layout: row=quad*4+r, col=ct*16+l16)
#pragma unroll
    for (int cc = 0; cc < 2; ++cc)
#pragma unroll
        for (int r = 0; r < 4; ++r)
            hrow[(gr * 16 + quad * 4 + r) * XS + (ct0 + cc) * 16 + l16] =
                f2bf(fmaxf(acc[cc][r], 0.f));
    __syncthreads();

    // ---- layer 2: v = u @ W2 + b2 ----
    const u16* up = &hrow[(gr * 16 + l16) * XS + quad * 8];
    bf16x8 u0 = *(const bf16x8*)up;
    bf16x8 u1 = *(const bf16x8*)(up + 32);

#pragma unroll
    for (int cc = 0; cc < 2; ++cc) {
        int ct = ct0 + cc;
        float bv = b2[ct * 16 + l16];
        acc[cc] = (f32x4){bv, bv, bv, bv};
        bf16x8 bf0 = *(const bf16x8*)(Wf + (size_t)((1 * 4 + ct) * 2 + 0) * 512 + lane * 8);
        bf16x8 bf1 = *(const bf16x8*)(Wf + (size_t)((1 * 4 + ct) * 2 + 1) * 512 + lane * 8);
        acc[cc] = __builtin_amdgcn_mfma_f32_16x16x32_bf16(u0, bf0, acc[cc], 0, 0, 0);
        acc[cc] = __builtin_amdgcn_mfma_f32_16x16x32_bf16(u1, bf1, acc[cc], 0, 0, 0);
    }

    // epilogue (C-layout scatter; 16-lane groups write contiguous runs)
#pragma unroll
    for (int r = 0; r < 4; ++r) {
        int nd = nbase + gr * 16 + quad * 4 + r;
#pragma unroll
        for (int cc = 0; cc < 2; ++cc) {
            int ct = ct0 + cc;
            if (WRITE_BF16)
                outb[(size_t)nd * D + ct * 16 + l16] = f2bf(fmaxf(acc[cc][r], 0.f));
            else
                outf[(size_t)nd * D + ct * 16 + l16] = acc[cc][r];
        }
    }
}

extern "C" void kernel_launch(void* const* d_in, const int* in_sizes, int n_in,
                              void* d_out, int out_size, void* d_ws, size_t ws_size,
                              hipStream_t stream)
{
    const float* x  = (const float*)d_in[0];
    const int*   ei = (const int*)d_in[1];
    const float* W1 = (const float*)d_in[2];
    const float* b1 = (const float*)d_in[3];
    const float* W2 = (const float*)d_in[4];
    const float* b2 = (const float*)d_in[5];
    float* out = (float*)d_out;

    // workspace (~41.6 MB):
    //   qtail(1024) | cnt(100096) | row_start(100096)
    //   queue (782*2432 u32) | sorted_src (782*2432 int)
    //   Wf (8192 u16) | hb ((N+1) rows bf16) | xb ((N+1) rows bf16)
    int* qtail      = (int*)d_ws;
    int* cnt_arr    = qtail + 1024;
    int* row_start  = cnt_arr + 100096;
    unsigned* queue = (unsigned*)(row_start + 100096);
    int* sorted_src = (int*)(queue + (size_t)NBUCKET * QCAP_B);
    u16* Wf         = (u16*)(sorted_src + (size_t)NBUCKET * QCAP_B);
    u16* hb_b       = Wf + 8192;
    u16* xb_b       = hb_b + (size_t)(N_NODES + 1) * D;

    const int fused_blocks = (N_NODES + 31) / 32;   // 3125 (32 nodes/block)

    // ---- prep: misc (qtail, dummy rows, weights) then sort(+convert) ----
    misc_kernel<<<1, 256, 0, stream>>>(W1, W2, Wf, qtail, xb_b, hb_b);
    sort_kernel<<<SORT_BLOCKS, 1024, 0, stream>>>(ei, qtail, queue, x, xb_b);
    bin3_kernel<<<NBUCKET, 512, 0, stream>>>(queue, qtail, cnt_arr, row_start, sorted_src);

    // ---- layer 1: hb = relu(MLP(xb + gather(xb))) ----
    gin_fused_kernel<1><<<fused_blocks, 256, 0, stream>>>(
        xb_b, cnt_arr, row_start, sorted_src, Wf, b1, b2, nullptr, hb_b);

    // ---- layer 2: out = MLP(hb + gather(hb)) ----
    gin_fused_kernel<0><<<fused_blocks, 256, 0, stream>>>(
        hb_b, cnt_arr, row_start, sorted_src, Wf, b1, b2, out, nullptr);
}